// Round 3
// baseline (64.559 us; speedup 1.0000x reference)
//
#include <hip/hip_runtime.h>

#define IN_CH 16
#define OUT_CH 32
#define NUM_INPUTS 144   // IN_CH * 3 * 3
#define H_ 32
#define W_ 32
#define NTAB 2304        // NUM_INPUTS * 16 och-pairs

typedef __attribute__((ext_vector_type(2))) float f32x2;
typedef __attribute__((ext_vector_type(4))) float f32x4;

// ws layout (floats):
//   [0      .. 9216)   tAg : 2304 x f32x4  (p1a,p1b,m0a,m0b)
//   [9216   .. 13824)  tDg : 2304 x f32x2  (dma,dmb)
//   [13824  .. 14112)  B0p : 9 blocks x 16 x f32x2 (b0 partials)
#define WS_TD 9216
#define WS_B0 13824

// ---------------------------------------------------------------------------
// R9 = R8 resubmit (R8 failed on a transient container error, not a kernel
// fault: no OOB, no hang path, no graph-capture violation in audit).
//
// Design: R7 rebuilt the 55KB piecewise table in EVERY block: ~54 scattered
// scalar global loads/thread (24B-stride lanes -> ~20 lines per wave-instr),
// x512 blocks ~= 14M L2-latency-bound transactions + 512x redundant math.
// Now: apc_tables does it once (2304 threads, 1 entry each); apc_fused
// pulls the prebuilt tables with ~9 fully-coalesced vector loads/thread.
// ---------------------------------------------------------------------------
__global__ __launch_bounds__(256, 4) void apc_tables(
        const float* __restrict__ pos,
        const float* __restrict__ val,
        float* __restrict__ ws) {
    __shared__ f32x2 bpart[256];
    f32x4* tAg = (f32x4*)ws;
    f32x2* tDg = (f32x2*)(ws + WS_TD);
    f32x2* B0p = (f32x2*)(ws + WS_B0);

    int tid = threadIdx.x;
    int e   = blockIdx.x * 256 + tid;     // 0..2303, exact
    int i   = e >> 4;                     // tap index
    int op  = e & 15;                     // och pair (2op, 2op+1)

    // 6 consecutive floats per (i, op-pair): [q0a q1a q2a q0b q1b q2b]
    const float* pp = pos + i * 96 + op * 6;   // 8B-aligned (24B stride)
    const float* vv = val + i * 96 + op * 6;
    f32x2 pu0 = *(const f32x2*)(pp);
    f32x2 pu1 = *(const f32x2*)(pp + 2);
    f32x2 pu2 = *(const f32x2*)(pp + 4);
    f32x2 vu0 = *(const f32x2*)(vv);
    f32x2 vu1 = *(const f32x2*)(vv + 2);
    f32x2 vu2 = *(const f32x2*)(vv + 4);
    float q0a = pu0.x, q1a = pu0.y, q2a = pu1.x;
    float q0b = pu1.y, q1b = pu2.x, q2b = pu2.y;
    float w0a = vu0.x, w1a = vu0.y, w2a = vu1.x;
    float w0b = vu1.y, w1b = vu2.x, w2b = vu2.y;

    float s0a = (w1a - w0a) * __builtin_amdgcn_rcpf(q1a - q0a);
    float s1a = (w2a - w1a) * __builtin_amdgcn_rcpf(q2a - q1a);
    float s0b = (w1b - w0b) * __builtin_amdgcn_rcpf(q1b - q0b);
    float s1b = (w2b - w1b) * __builtin_amdgcn_rcpf(q2b - q1b);

    tAg[e] = (f32x4){q1a, q1b, s0a, s0b};
    tDg[e] = (f32x2){s1a - s0a, s1b - s0b};

    // per-block b0 partial sum by och-pair
    bpart[tid] = (f32x2){w0a - s0a * q0a, w0b - s0b * q0b};
    __syncthreads();
    if (tid < 16) {
        f32x2 s = {0.f, 0.f};
        #pragma unroll
        for (int g = 0; g < 16; ++g) s += bpart[g * 16 + tid];
        B0p[blockIdx.x * 16 + tid] = s;
    }
}

// ---------------------------------------------------------------------------
// Spatial kernel: grid 512 x 512 thr (8 waves). Block = 16 positions
// (2 rows x 8 cols) x all 32 och. Lane = sg(4 pos-groups) x op(16 och-pairs);
// wave = 2 input channels (tap-split 8-way, LDS reduction aliasing ltA).
// LDS 59.5 KB -> 2 blocks/CU -> 4 waves/SIMD.
// ---------------------------------------------------------------------------
__global__ __launch_bounds__(512, 4) void apc_fused(
        const float* __restrict__ x,
        const float* __restrict__ ws,
        float* __restrict__ out) {
    __shared__ f32x4 ltA[NTAB];              // 36864 B  (p1a,p1b,m0a,m0b)
    __shared__ f32x2 ltD[NTAB];              // 18432 B  (dma,dmb)
    __shared__ float lx[IN_CH * 4 * 16];     //  4096 B  padded 2x8 tile
    __shared__ f32x2 B0f[16];                //   128 B
    // reduction buffer (16 KB) aliases ltA after the main loop.

    int tid  = threadIdx.x;
    int bx   = blockIdx.x;           // 0..511
    int b    = bx >> 6;              // batch
    int t64  = bx & 63;              // 16 row-pairs x 4 col-octets
    int row0 = (t64 >> 2) * 2;
    int col0 = (t64 & 3) * 8;

    // ---- Phase 0a: stage 16ch x 4rows x 10cols (stride 16), zero-padded. --
    #pragma unroll
    for (int it = 0; it < 2; ++it) {
        int s  = tid + it * 512;
        int c  = s >> 6;
        int rr = (s >> 4) & 3;       // padded row: global row0+rr-1
        int cl = s & 15;             // padded col: global col0+cl-1
        int gr = row0 + rr - 1;
        int gc = col0 + cl - 1;
        float v = 0.f;
        if (cl < 10 && (unsigned)gr < (unsigned)H_ && (unsigned)gc < (unsigned)W_)
            v = x[((b * IN_CH + c) * H_ + gr) * W_ + gc];
        lx[s] = v;
    }

    // ---- Phase 0b: coalesced table pull from ws (built by apc_tables). ----
    {
        const f32x4* tAg = (const f32x4*)ws;
        const f32x2* tDg = (const f32x2*)(ws + WS_TD);
        #pragma unroll
        for (int it = 0; it < 4; ++it) {
            int e = tid + it * 512;
            ltA[e] = tAg[e];
            ltD[e] = tDg[e];
        }
        int e4 = tid + 2048;
        if (e4 < NTAB) { ltA[e4] = tAg[e4]; ltD[e4] = tDg[e4]; }
        if (tid < 16) {
            const f32x2* B0p = (const f32x2*)(ws + WS_B0);
            f32x2 s = {0.f, 0.f};
            #pragma unroll
            for (int g = 0; g < 9; ++g) s += B0p[g * 16 + tid];
            B0f[tid] = s;
        }
    }
    __syncthreads();

    // ---- Main loop: wave = channels {2w,2w+1}; lane = (sg, op). -----------
    int wid  = tid >> 6;             // 0..7
    int lane = tid & 63;
    int sg   = lane >> 4;            // position group
    int op   = lane & 15;            // och pair
    int r0   = sg >> 1;              // local output row 0/1
    int cb   = (sg & 1) * 4;         // col base 0/4
    int c0   = wid * 2;

    f32x2 aacc[4], hacc[4];
    const f32x2 zz = {0.f, 0.f};
    #pragma unroll
    for (int j = 0; j < 4; ++j) { aacc[j] = zz; hacc[j] = zz; }

    const float* lxb = lx + (c0 * 4 + r0) * 16 + cb;   // 16B-aligned
    const f32x4* Ab  = ltA + c0 * 144 + op;
    const f32x2* Db  = ltD + c0 * 144 + op;

    #pragma unroll
    for (int dc = 0; dc < 2; ++dc) {
        // preload 3 padded rows x 6 cols -> covers all (kh,kw,j) windows
        float w[3][6];
        #pragma unroll
        for (int dr = 0; dr < 3; ++dr) {
            f32x4 u = *(const f32x4*)(lxb + (dc * 4 + dr) * 16);
            f32x2 v = *(const f32x2*)(lxb + (dc * 4 + dr) * 16 + 4);
            w[dr][0] = u.x; w[dr][1] = u.y; w[dr][2] = u.z; w[dr][3] = u.w;
            w[dr][4] = v.x; w[dr][5] = v.y;
        }
        #pragma unroll
        for (int kh = 0; kh < 3; ++kh) {
            #pragma unroll
            for (int kw = 0; kw < 3; ++kw) {
                int ti = (dc * 9 + kh * 3 + kw) * 16;  // compile-time offset
                f32x4 A = Ab[ti];
                f32x2 D = Db[ti];
                f32x2 P = {A.x, A.y};
                f32x2 M = {A.z, A.w};
                #pragma unroll
                for (int j = 0; j < 4; ++j) {
                    f32x2 q = {w[kh][kw + j], w[kh][kw + j]};
                    aacc[j] = __builtin_elementwise_fma(M, q, aacc[j]);
                    hacc[j] = __builtin_elementwise_fma(
                        D, __builtin_elementwise_max(q - P, zz), hacc[j]);
                }
            }
        }
    }

    // ---- Tap-split combine: red aliases ltA (tables dead now). ------------
    __syncthreads();                 // all table/lx reads complete
    {
        f32x2 s0 = aacc[0] + hacc[0], s1 = aacc[1] + hacc[1];
        f32x2 s2 = aacc[2] + hacc[2], s3 = aacc[3] + hacc[3];
        int rb = (wid * 64 + lane) * 2;
        ltA[rb + 0] = (f32x4){s0.x, s0.y, s1.x, s1.y};
        ltA[rb + 1] = (f32x4){s2.x, s2.y, s3.x, s3.y};
    }
    __syncthreads();

    if (tid < 256) {
        const f32x2* red = (const f32x2*)ltA;
        int opx = tid >> 4;          // och pair
        int p   = tid & 15;          // position (cols fastest -> coalesced)
        int rr  = p >> 3;
        int cl  = p & 7;
        int sgx = rr * 2 + (cl >> 2);
        int j   = cl & 3;
        int base = (sgx * 16 + opx) * 4 + j;
        f32x2 s = B0f[opx];
        #pragma unroll
        for (int wv = 0; wv < 8; ++wv) s += red[wv * 256 + base];
        int oidx = ((b * OUT_CH + 2 * opx) * H_ + (row0 + rr)) * W_ + (col0 + cl);
        out[oidx]            = s.x;
        out[oidx + H_ * W_]  = s.y;
    }
}

extern "C" void kernel_launch(void* const* d_in, const int* in_sizes, int n_in,
                              void* d_out, int out_size, void* d_ws, size_t ws_size,
                              hipStream_t stream) {
    const float* x   = (const float*)d_in[0];
    const float* pos = (const float*)d_in[1];
    const float* val = (const float*)d_in[2];
    float*       ws  = (float*)d_ws;

    apc_tables<<<dim3(9),   dim3(256), 0, stream>>>(pos, val, ws);
    apc_fused <<<dim3(512), dim3(512), 0, stream>>>(x, ws, (float*)d_out);
}